// Round 7
// baseline (187.048 us; speedup 1.0000x reference)
//
#include <hip/hip_runtime.h>

#define Bv 2
#define Nv 5000
#define Cv 768
#define Hv 12
#define Dv 64
#define Ev 160000
#define ETOT (Ev + Nv)   // 165000 (edges + self loops)
#define HD 768
#define NEG 0.2f
#define Mv (Bv * Nv)     // 10000
#define MPAD 10112       // 79 * 128
#define DEGMAX 128       // max in-degree incl. self-loop; Poisson(33) tail -> safe

typedef __bf16 bf16x8 __attribute__((ext_vector_type(8)));
typedef float f32x4 __attribute__((ext_vector_type(4)));

// direct-to-LDS 16B async copy
#define GLD16(gsrc, ldst)                                                      \
  __builtin_amdgcn_global_load_lds(                                            \
      (const __attribute__((address_space(1))) unsigned int*)(gsrc),           \
      (__attribute__((address_space(3))) unsigned int*)(ldst), 16, 0, 0)

// f32 -> bf16 round-to-nearest-even
__device__ __forceinline__ unsigned short f2b(float f) {
  unsigned u = __float_as_uint(f);
  return (unsigned short)((u + 0x7FFFu + ((u >> 16) & 1u)) >> 16);
}
__device__ __forceinline__ float b2f(unsigned short b) {
  return __uint_as_float((unsigned)b << 16);
}

// ---------------- convert x -> bf16, padded to MPAD rows -------------------
__global__ __launch_bounds__(256) void k_cvt_x(const float* __restrict__ x,
                                               unsigned short* __restrict__ xb) {
  size_t i = ((size_t)blockIdx.x * 256 + threadIdx.x) * 8;
  if (i >= (size_t)MPAD * Cv) return;
  unsigned short o[8];
  if (i < (size_t)Mv * Cv) {
    float4 v0 = *(const float4*)(x + i);
    float4 v1 = *(const float4*)(x + i + 4);
    o[0] = f2b(v0.x); o[1] = f2b(v0.y); o[2] = f2b(v0.z); o[3] = f2b(v0.w);
    o[4] = f2b(v1.x); o[5] = f2b(v1.y); o[6] = f2b(v1.z); o[7] = f2b(v1.w);
  } else {
    for (int j = 0; j < 8; ++j) o[j] = 0;
  }
  *(uint4*)(xb + i) = *(const uint4*)o;
}

// ---------------- transpose+convert W[k][n] -> Wt[n][k] bf16 ---------------
__global__ __launch_bounds__(256) void k_cvt_wt(const float* __restrict__ W,
                                                unsigned short* __restrict__ Wt) {
  __shared__ float s[32][33];
  const int k0 = blockIdx.y * 32, n0 = blockIdx.x * 32;
  const int tx = threadIdx.x, ty = threadIdx.y;  // 32 x 8
#pragma unroll
  for (int i = 0; i < 4; ++i)
    s[ty + i * 8][tx] = W[(size_t)(k0 + ty + i * 8) * HD + n0 + tx];
  __syncthreads();
#pragma unroll
  for (int i = 0; i < 4; ++i)
    Wt[(size_t)(n0 + ty + i * 8) * Cv + k0 + tx] = f2b(s[tx][ty + i * 8]);
}

// ---------------- GEMM: h2[MPAD,768] = xb @ Wt^T (bf16 MFMA, bf16 out) -----
__global__ __launch_bounds__(256) void k_gemm_mfma(const unsigned short* __restrict__ A,
                                                   const unsigned short* __restrict__ Bt,
                                                   unsigned short* __restrict__ C) {
  __shared__ unsigned short As[128 * 64];
  __shared__ unsigned short Bs[128 * 64];
  const int t = threadIdx.x;
  const int w = t >> 6, l = t & 63;
  const int wr = w >> 1, wc = w & 1;
  const int bm = blockIdx.y * 128, bn = blockIdx.x * 128;
  const int g = l >> 4, li = l & 15;
  f32x4 acc[4][4] = {};

  const int rs = t >> 3;              // staging row within 32-row issue
  const int sl = (t & 7) ^ (rs & 7);  // pre-swizzled logical slot for source

  for (int k0 = 0; k0 < Cv; k0 += 64) {
#pragma unroll
    for (int i = 0; i < 4; ++i) {
      const int r = i * 32 + rs;
      GLD16(A + (size_t)(bm + r) * Cv + k0 + sl * 8, &As[t * 8 + i * 2048]);
      GLD16(Bt + (size_t)(bn + r) * Cv + k0 + sl * 8, &Bs[t * 8 + i * 2048]);
    }
    __syncthreads();  // drains vmcnt(0): LDS tiles ready for all waves
#pragma unroll
    for (int ks = 0; ks < 2; ++ks) {
      bf16x8 a[4], b[4];
#pragma unroll
      for (int mi = 0; mi < 4; ++mi) {
        const int row = wr * 64 + mi * 16 + li;
        const int slot = (ks * 4 + g) ^ (row & 7);
        a[mi] = *(const bf16x8*)&As[row * 64 + slot * 8];
      }
#pragma unroll
      for (int nj = 0; nj < 4; ++nj) {
        const int row = wc * 64 + nj * 16 + li;
        const int slot = (ks * 4 + g) ^ (row & 7);
        b[nj] = *(const bf16x8*)&Bs[row * 64 + slot * 8];
      }
#pragma unroll
      for (int mi = 0; mi < 4; ++mi)
#pragma unroll
        for (int nj = 0; nj < 4; ++nj)
          acc[mi][nj] = __builtin_amdgcn_mfma_f32_16x16x32_bf16(a[mi], b[nj], acc[mi][nj], 0, 0, 0);
    }
    __syncthreads();  // protect LDS before next stage
  }
  // C/D layout: col = lane&15, row = (lane>>4)*4 + reg (m89-verified)
#pragma unroll
  for (int mi = 0; mi < 4; ++mi) {
#pragma unroll
    for (int nj = 0; nj < 4; ++nj) {
      const int col = bn + wc * 64 + nj * 16 + li;
#pragma unroll
      for (int r4 = 0; r4 < 4; ++r4) {
        const int row = bm + wr * 64 + mi * 16 + g * 4 + r4;
        C[(size_t)row * HD + col] = f2b(acc[mi][nj][r4]);
      }
    }
  }
}

// ---------------- attention dots from bf16 h -------------------------------
__global__ void k_att(const unsigned short* __restrict__ h2, const float* __restrict__ att_src,
                      const float* __restrict__ att_dst, float* __restrict__ asrc,
                      float* __restrict__ adst) {
  int w = (blockIdx.x * blockDim.x + threadIdx.x) >> 6;  // one wave per (b,n,h)
  int lane = threadIdx.x & 63;
  if (w >= Bv * Nv * Hv) return;
  int hh = w % Hv;
  int bn = w / Hv;
  float hv = b2f(h2[(size_t)bn * HD + hh * Dv + lane]);
  float vs = hv * att_src[hh * Dv + lane];
  float vd = hv * att_dst[hh * Dv + lane];
  for (int off = 32; off; off >>= 1) {
    vs += __shfl_xor(vs, off);
    vd += __shfl_xor(vd, off);
  }
  if (lane == 0) { asrc[w] = vs; adst[w] = vd; }
}

// ---------------- CSR build ------------------------------------------------
__global__ void k_count(const int* __restrict__ ei, int* __restrict__ counts) {
  int e = blockIdx.x * blockDim.x + threadIdx.x;
  if (e >= ETOT) return;
  int dst = (e < Ev) ? ei[Ev + e] : (e - Ev);
  atomicAdd(&counts[dst], 1);
}

__global__ void k_scan(const int* __restrict__ counts, int* __restrict__ offsets) {
  __shared__ int part[256];
  const int t = threadIdx.x;
  const int chunk = (Nv + 255) / 256;  // 20
  int begin = t * chunk;
  int end = begin + chunk;
  if (end > Nv) end = Nv;
  if (begin > Nv) begin = Nv;
  int s = 0;
  for (int i = begin; i < end; ++i) s += counts[i];
  part[t] = s;
  __syncthreads();
  for (int off = 1; off < 256; off <<= 1) {
    int v = (t >= off) ? part[t - off] : 0;
    __syncthreads();
    part[t] += v;
    __syncthreads();
  }
  int run = (t == 0) ? 0 : part[t - 1];
  for (int i = begin; i < end; ++i) {
    offsets[i] = run;
    run += counts[i];
  }
  if (t == 0) offsets[Nv] = ETOT;
}

__global__ void k_scatter(const int* __restrict__ ei, const int* __restrict__ offsets,
                          int* __restrict__ cursor, int* __restrict__ csr) {
  int e = blockIdx.x * blockDim.x + threadIdx.x;
  if (e >= ETOT) return;
  int dst = (e < Ev) ? ei[Ev + e] : (e - Ev);
  int pos = atomicAdd(&cursor[dst], 1);
  csr[offsets[dst] + pos] = e;
}

// ------- fused softmax + aggregation: block per n, BOTH batches ------------
// 384 threads = 2 x 192; bb = t/192 selects batch. Shared s_src staging.
// Phase A: 24 groups of 16 lanes -> (bb,hh); exp weights + shuffle denom.
// Phase B: per-batch 192-lane row gather (ushort4/lane), 4-deep prefetch.
// No max subtraction (logits O(1), f32-safe; softmax shift-invariant).
__global__ __launch_bounds__(384) void k_agg(const unsigned short* __restrict__ h2,
                                             const int* __restrict__ ei,
                                             const int* __restrict__ offsets,
                                             const int* __restrict__ csr,
                                             const float* __restrict__ asrc,
                                             const float* __restrict__ adst,
                                             const float* __restrict__ bias,
                                             float* __restrict__ out) {
  const int n = blockIdx.x;
  const int t = threadIdx.x;
  __shared__ int s_src[DEGMAX];
  __shared__ float s_w[DEGMAX][Bv * Hv];
  __shared__ float s_inv[Bv * Hv];
  const int beg = offsets[n];
  const int deg = offsets[n + 1] - beg;  // <= DEGMAX
  if (t < deg) {
    int e = csr[beg + t];
    s_src[t] = (e < Ev) ? ei[e] : (e - Ev);
  }
  __syncthreads();
  {
    const int grp = t >> 4;           // 0..23 = bb*12 + hh
    const int j = t & 15;
    const int ba = grp / Hv, hh = grp % Hv;
    const float adv = adst[((size_t)ba * Nv + n) * Hv + hh];
    float ps = 0.f;
#pragma unroll
    for (int k = 0; k < 8; ++k) {
      const int i = j + k * 16;
      if (i < deg) {
        float v = asrc[((size_t)ba * Nv + s_src[i]) * Hv + hh] + adv;
        v = (v > 0.f) ? v : NEG * v;
        float ex = __expf(v);
        s_w[i][grp] = ex;
        ps += ex;
      }
    }
    ps += __shfl_xor(ps, 1);
    ps += __shfl_xor(ps, 2);
    ps += __shfl_xor(ps, 4);
    ps += __shfl_xor(ps, 8);
    if (j == 0) s_inv[grp] = 1.0f / (ps + 1e-16f);
  }
  __syncthreads();
  // Phase B: batch bb, lane tl owns dims [4tl, 4tl+4)
  const int bb = t / 192;
  const int tl = t - bb * 192;
  const int wgrp = bb * Hv + (tl >> 4);
  const float invh = s_inv[wgrp];
  float acc0 = 0.f, acc1 = 0.f, acc2 = 0.f, acc3 = 0.f;
  const size_t hbase = (size_t)bb * Nv * HD + tl * 4;
  ushort4 p0 = {0, 0, 0, 0}, p1 = p0, p2 = p0, p3 = p0;
  if (0 < deg) p0 = *(const ushort4*)(h2 + hbase + (size_t)s_src[0] * HD);
  if (1 < deg) p1 = *(const ushort4*)(h2 + hbase + (size_t)s_src[1] * HD);
  if (2 < deg) p2 = *(const ushort4*)(h2 + hbase + (size_t)s_src[2] * HD);
  if (3 < deg) p3 = *(const ushort4*)(h2 + hbase + (size_t)s_src[3] * HD);
  for (int i = 0; i < deg; ++i) {
    ushort4 cur = p0;
    p0 = p1; p1 = p2; p2 = p3;
    if (i + 4 < deg) p3 = *(const ushort4*)(h2 + hbase + (size_t)s_src[i + 4] * HD);
    const float w = s_w[i][wgrp] * invh;
    acc0 = fmaf(w, b2f(cur.x), acc0);
    acc1 = fmaf(w, b2f(cur.y), acc1);
    acc2 = fmaf(w, b2f(cur.z), acc2);
    acc3 = fmaf(w, b2f(cur.w), acc3);
  }
  const int od = tl * 4;
  float4 o;
  o.x = acc0 + bias[od + 0];
  o.y = acc1 + bias[od + 1];
  o.z = acc2 + bias[od + 2];
  o.w = acc3 + bias[od + 3];
  *(float4*)(out + ((size_t)bb * Nv + n) * HD + od) = o;
}

extern "C" void kernel_launch(void* const* d_in, const int* in_sizes, int n_in,
                              void* d_out, int out_size, void* d_ws, size_t ws_size,
                              hipStream_t stream) {
  const float* x = (const float*)d_in[0];
  const float* W = (const float*)d_in[1];
  const float* att_src = (const float*)d_in[2];
  const float* att_dst = (const float*)d_in[3];
  const float* bias = (const float*)d_in[4];
  const int* ei = (const int*)d_in[5];
  float* out = (float*)d_out;

  // workspace layout
  unsigned short* h2 = (unsigned short*)d_ws;            // MPAD*768 bf16
  unsigned short* xbf = h2 + (size_t)MPAD * HD;          // MPAD*768 bf16
  unsigned short* wt = xbf + (size_t)MPAD * HD;          // 768*768 bf16
  float* asrc = (float*)(wt + (size_t)HD * Cv);          // 120,000 f32
  float* adst = asrc + (size_t)Bv * Nv * Hv;             // 120,000 f32
  int* counts = (int*)(adst + (size_t)Bv * Nv * Hv);     // Nv
  int* cursor = counts + Nv;                             // Nv
  int* offsets = cursor + Nv;                            // Nv+1
  int* csr = offsets + Nv + 1;                           // ETOT

  hipMemsetAsync(counts, 0, sizeof(int) * 2 * Nv, stream);

  k_cvt_x<<<(int)(((size_t)MPAD * HD / 8 + 255) / 256), 256, 0, stream>>>(x, xbf);
  k_cvt_wt<<<dim3(HD / 32, Cv / 32), dim3(32, 8), 0, stream>>>(W, wt);
  k_gemm_mfma<<<dim3(HD / 128, MPAD / 128), 256, 0, stream>>>(xbf, wt, h2);
  k_att<<<(Bv * Nv * Hv + 3) / 4, 256, 0, stream>>>(h2, att_src, att_dst, asrc, adst);
  k_count<<<(ETOT + 255) / 256, 256, 0, stream>>>(ei, counts);
  k_scan<<<1, 256, 0, stream>>>(counts, offsets);
  k_scatter<<<(ETOT + 255) / 256, 256, 0, stream>>>(ei, offsets, cursor, csr);
  k_agg<<<Nv, 384, 0, stream>>>(h2, ei, offsets, csr, asrc, adst, bias, out);
}

// Round 8
// 141.943 us; speedup vs baseline: 1.3178x; 1.3178x over previous
//
#include <hip/hip_runtime.h>

#define Bv 2
#define Nv 5000
#define Cv 768
#define Hv 12
#define Dv 64
#define Ev 160000
#define ETOT (Ev + Nv)   // 165000 (edges + self loops)
#define HD 768
#define NEG 0.2f
#define Mv (Bv * Nv)     // 10000
#define MPAD 10112       // 79 * 128
#define DEGMAX 128       // max in-degree incl. self-loop; Poisson(33) tail -> safe

typedef __bf16 bf16x8 __attribute__((ext_vector_type(8)));
typedef float f32x4 __attribute__((ext_vector_type(4)));

// direct-to-LDS 16B async copy
#define GLD16(gsrc, ldst)                                                      \
  __builtin_amdgcn_global_load_lds(                                            \
      (const __attribute__((address_space(1))) unsigned int*)(gsrc),           \
      (__attribute__((address_space(3))) unsigned int*)(ldst), 16, 0, 0)

// f32 -> bf16 round-to-nearest-even
__device__ __forceinline__ unsigned short f2b(float f) {
  unsigned u = __float_as_uint(f);
  return (unsigned short)((u + 0x7FFFu + ((u >> 16) & 1u)) >> 16);
}
__device__ __forceinline__ float b2f(unsigned short b) {
  return __uint_as_float((unsigned)b << 16);
}

// ---------------- convert x -> bf16, padded to MPAD rows -------------------
__global__ __launch_bounds__(256) void k_cvt_x(const float* __restrict__ x,
                                               unsigned short* __restrict__ xb) {
  size_t i = ((size_t)blockIdx.x * 256 + threadIdx.x) * 8;
  if (i >= (size_t)MPAD * Cv) return;
  unsigned short o[8];
  if (i < (size_t)Mv * Cv) {
    float4 v0 = *(const float4*)(x + i);
    float4 v1 = *(const float4*)(x + i + 4);
    o[0] = f2b(v0.x); o[1] = f2b(v0.y); o[2] = f2b(v0.z); o[3] = f2b(v0.w);
    o[4] = f2b(v1.x); o[5] = f2b(v1.y); o[6] = f2b(v1.z); o[7] = f2b(v1.w);
  } else {
    for (int j = 0; j < 8; ++j) o[j] = 0;
  }
  *(uint4*)(xb + i) = *(const uint4*)o;
}

// ---------------- transpose+convert W[k][n] -> Wt[n][k] bf16 ---------------
__global__ __launch_bounds__(256) void k_cvt_wt(const float* __restrict__ W,
                                                unsigned short* __restrict__ Wt) {
  __shared__ float s[32][33];
  const int k0 = blockIdx.y * 32, n0 = blockIdx.x * 32;
  const int tx = threadIdx.x, ty = threadIdx.y;  // 32 x 8
#pragma unroll
  for (int i = 0; i < 4; ++i)
    s[ty + i * 8][tx] = W[(size_t)(k0 + ty + i * 8) * HD + n0 + tx];
  __syncthreads();
#pragma unroll
  for (int i = 0; i < 4; ++i)
    Wt[(size_t)(n0 + ty + i * 8) * Cv + k0 + tx] = f2b(s[tx][ty + i * 8]);
}

// ------ GEMM + fused attention dots: h2 = xb @ Wt^T; asrc/adst epilogue ----
// Each 128-col tile covers exactly 2 heads (64 dims each), so the full
// per-head dot <h_row, att_head> is computable from this block's acc frags:
// per-lane 4 FMA over nj, then 16-lane shfl reduce over li. No atomics.
__global__ __launch_bounds__(256) void k_gemm_mfma(const unsigned short* __restrict__ A,
                                                   const unsigned short* __restrict__ Bt,
                                                   unsigned short* __restrict__ C,
                                                   const float* __restrict__ att_src,
                                                   const float* __restrict__ att_dst,
                                                   float* __restrict__ asrc,
                                                   float* __restrict__ adst) {
  __shared__ unsigned short As[128 * 64];
  __shared__ unsigned short Bs[128 * 64];
  const int t = threadIdx.x;
  const int w = t >> 6, l = t & 63;
  const int wr = w >> 1, wc = w & 1;
  const int bm = blockIdx.y * 128, bn = blockIdx.x * 128;
  const int g = l >> 4, li = l & 15;
  f32x4 acc[4][4] = {};

  const int rs = t >> 3;              // staging row within 32-row issue
  const int sl = (t & 7) ^ (rs & 7);  // pre-swizzled logical slot for source

  for (int k0 = 0; k0 < Cv; k0 += 64) {
#pragma unroll
    for (int i = 0; i < 4; ++i) {
      const int r = i * 32 + rs;
      GLD16(A + (size_t)(bm + r) * Cv + k0 + sl * 8, &As[t * 8 + i * 2048]);
      GLD16(Bt + (size_t)(bn + r) * Cv + k0 + sl * 8, &Bs[t * 8 + i * 2048]);
    }
    __syncthreads();  // drains vmcnt(0): LDS tiles ready for all waves
#pragma unroll
    for (int ks = 0; ks < 2; ++ks) {
      bf16x8 a[4], b[4];
#pragma unroll
      for (int mi = 0; mi < 4; ++mi) {
        const int row = wr * 64 + mi * 16 + li;
        const int slot = (ks * 4 + g) ^ (row & 7);
        a[mi] = *(const bf16x8*)&As[row * 64 + slot * 8];
      }
#pragma unroll
      for (int nj = 0; nj < 4; ++nj) {
        const int row = wc * 64 + nj * 16 + li;
        const int slot = (ks * 4 + g) ^ (row & 7);
        b[nj] = *(const bf16x8*)&Bs[row * 64 + slot * 8];
      }
#pragma unroll
      for (int mi = 0; mi < 4; ++mi)
#pragma unroll
        for (int nj = 0; nj < 4; ++nj)
          acc[mi][nj] = __builtin_amdgcn_mfma_f32_16x16x32_bf16(a[mi], b[nj], acc[mi][nj], 0, 0, 0);
    }
    __syncthreads();  // protect LDS before next stage
  }
  // C/D layout: col = lane&15, row = (lane>>4)*4 + reg (m89-verified)
#pragma unroll
  for (int mi = 0; mi < 4; ++mi) {
#pragma unroll
    for (int nj = 0; nj < 4; ++nj) {
      const int col = bn + wc * 64 + nj * 16 + li;
#pragma unroll
      for (int r4 = 0; r4 < 4; ++r4) {
        const int row = bm + wr * 64 + mi * 16 + g * 4 + r4;
        C[(size_t)row * HD + col] = f2b(acc[mi][nj][r4]);
      }
    }
  }
  // fused attention-dot epilogue: head covered by this wave's 64 cols
  {
    const int head = (bn >> 6) + wc;  // 2*blockIdx.x + wc
    float aS[4], aD[4];
#pragma unroll
    for (int nj = 0; nj < 4; ++nj) {
      aS[nj] = att_src[head * Dv + nj * 16 + li];
      aD[nj] = att_dst[head * Dv + nj * 16 + li];
    }
#pragma unroll
    for (int mi = 0; mi < 4; ++mi) {
#pragma unroll
      for (int r4 = 0; r4 < 4; ++r4) {
        float vs = 0.f, vd = 0.f;
#pragma unroll
        for (int nj = 0; nj < 4; ++nj) {
          const float hv = acc[mi][nj][r4];
          vs = fmaf(hv, aS[nj], vs);
          vd = fmaf(hv, aD[nj], vd);
        }
        vs += __shfl_xor(vs, 1); vd += __shfl_xor(vd, 1);
        vs += __shfl_xor(vs, 2); vd += __shfl_xor(vd, 2);
        vs += __shfl_xor(vs, 4); vd += __shfl_xor(vd, 4);
        vs += __shfl_xor(vs, 8); vd += __shfl_xor(vd, 8);
        const int row = bm + wr * 64 + mi * 16 + g * 4 + r4;
        if (li == 0 && row < Mv) {
          asrc[(size_t)row * Hv + head] = vs;
          adst[(size_t)row * Hv + head] = vd;
        }
      }
    }
  }
}

// ---------------- CSR build ------------------------------------------------
__global__ void k_count(const int* __restrict__ ei, int* __restrict__ counts) {
  int e = blockIdx.x * blockDim.x + threadIdx.x;
  if (e >= ETOT) return;
  int dst = (e < Ev) ? ei[Ev + e] : (e - Ev);
  atomicAdd(&counts[dst], 1);
}

__global__ __launch_bounds__(1024) void k_scan(const int* __restrict__ counts,
                                               int* __restrict__ offsets) {
  __shared__ int part[1024];
  const int t = threadIdx.x;
  const int chunk = 5;  // 1024*5 >= 5000
  int begin = t * chunk;
  int end = begin + chunk;
  if (end > Nv) end = Nv;
  if (begin > Nv) begin = Nv;
  int s = 0;
  for (int i = begin; i < end; ++i) s += counts[i];
  part[t] = s;
  __syncthreads();
  for (int off = 1; off < 1024; off <<= 1) {
    int v = (t >= off) ? part[t - off] : 0;
    __syncthreads();
    part[t] += v;
    __syncthreads();
  }
  int run = (t == 0) ? 0 : part[t - 1];
  for (int i = begin; i < end; ++i) {
    offsets[i] = run;
    run += counts[i];
  }
  if (t == 0) offsets[Nv] = ETOT;
}

__global__ void k_scatter(const int* __restrict__ ei, const int* __restrict__ offsets,
                          int* __restrict__ cursor, int* __restrict__ csr) {
  int e = blockIdx.x * blockDim.x + threadIdx.x;
  if (e >= ETOT) return;
  int dst = (e < Ev) ? ei[Ev + e] : (e - Ev);
  int pos = atomicAdd(&cursor[dst], 1);
  csr[offsets[dst] + pos] = e;
}

// ------- fused softmax + aggregation: block per (b,n), 192 threads ---------
// XCD-pinned: xcd = blk&7 (HW round-robin); batch = xcd>>2 so each XCD's L2
// only caches ONE batch's h2 (7.7 MB). No max subtraction (logits O(1)).
// Phase A: (hh=t>>4, j=t&15) exp weights + 4x shfl_xor denominator.
// Phase B: 192 lanes x ushort4; edges in chunks of 4, 2 chunk buffers
// (static indices), 4-8 loads in flight; 1/denom folded into final store.
__global__ __launch_bounds__(192) void k_agg(const unsigned short* __restrict__ h2,
                                             const int* __restrict__ ei,
                                             const int* __restrict__ offsets,
                                             const int* __restrict__ csr,
                                             const float* __restrict__ asrc,
                                             const float* __restrict__ adst,
                                             const float* __restrict__ bias,
                                             float* __restrict__ out) {
  const int xcd = blockIdx.x & 7;
  const int j0 = blockIdx.x >> 3;          // 0..1249
  const int b = xcd >> 2;
  const int n = (xcd & 3) * 1250 + j0;
  const int bn = b * Nv + n;
  const int t = threadIdx.x;
  __shared__ int s_src[DEGMAX];
  __shared__ float s_w[DEGMAX][Hv];
  __shared__ float s_inv[Hv];
  const int beg = offsets[n];
  const int deg = offsets[n + 1] - beg;  // <= DEGMAX
  if (t < DEGMAX) {
    int sv = 0;
    if (t < deg) {
      int e = csr[beg + t];
      sv = (e < Ev) ? ei[e] : (e - Ev);
    }
    s_src[t] = sv;  // pad with row 0 (safe to load, never consumed)
  }
  __syncthreads();
  {
    const int hh = t >> 4, jj = t & 15;
    const float adv = adst[(size_t)bn * Hv + hh];
    float ps = 0.f;
#pragma unroll
    for (int k = 0; k < 8; ++k) {
      const int i = jj + k * 16;
      if (i < deg) {
        float v = asrc[((size_t)b * Nv + s_src[i]) * Hv + hh] + adv;
        v = (v > 0.f) ? v : NEG * v;
        float ex = __expf(v);
        s_w[i][hh] = ex;
        ps += ex;
      }
    }
    ps += __shfl_xor(ps, 1);
    ps += __shfl_xor(ps, 2);
    ps += __shfl_xor(ps, 4);
    ps += __shfl_xor(ps, 8);
    if (jj == 0) s_inv[hh] = 1.0f / (ps + 1e-16f);
  }
  __syncthreads();
  // Phase B
  const int hl = t >> 4;
  float acc0 = 0.f, acc1 = 0.f, acc2 = 0.f, acc3 = 0.f;
  const size_t hbase = (size_t)b * Nv * HD + t * 4;
  ushort4 cA[4], cB[4];
#pragma unroll
  for (int k = 0; k < 4; ++k)
    cA[k] = *(const ushort4*)(h2 + hbase + (size_t)s_src[k] * HD);
  for (int base = 0; base < deg; base += 8) {
#pragma unroll
    for (int k = 0; k < 4; ++k) {
      const int i = base + 4 + k;
      cB[k] = *(const ushort4*)(h2 + hbase + (size_t)s_src[i < DEGMAX ? i : 0] * HD);
    }
#pragma unroll
    for (int k = 0; k < 4; ++k) {
      const int i = base + k;
      if (i < deg) {
        const float w = s_w[i][hl];
        acc0 = fmaf(w, b2f(cA[k].x), acc0);
        acc1 = fmaf(w, b2f(cA[k].y), acc1);
        acc2 = fmaf(w, b2f(cA[k].z), acc2);
        acc3 = fmaf(w, b2f(cA[k].w), acc3);
      }
    }
#pragma unroll
    for (int k = 0; k < 4; ++k) {
      const int i = base + 8 + k;
      cA[k] = *(const ushort4*)(h2 + hbase + (size_t)s_src[i < DEGMAX ? i : 0] * HD);
    }
#pragma unroll
    for (int k = 0; k < 4; ++k) {
      const int i = base + 4 + k;
      if (i < deg) {
        const float w = s_w[i][hl];
        acc0 = fmaf(w, b2f(cB[k].x), acc0);
        acc1 = fmaf(w, b2f(cB[k].y), acc1);
        acc2 = fmaf(w, b2f(cB[k].z), acc2);
        acc3 = fmaf(w, b2f(cB[k].w), acc3);
      }
    }
  }
  const float invh = s_inv[hl];
  const int od = t * 4;
  float4 o;
  o.x = fmaf(acc0, invh, bias[od + 0]);
  o.y = fmaf(acc1, invh, bias[od + 1]);
  o.z = fmaf(acc2, invh, bias[od + 2]);
  o.w = fmaf(acc3, invh, bias[od + 3]);
  *(float4*)(out + (size_t)bn * HD + od) = o;
}

extern "C" void kernel_launch(void* const* d_in, const int* in_sizes, int n_in,
                              void* d_out, int out_size, void* d_ws, size_t ws_size,
                              hipStream_t stream) {
  const float* x = (const float*)d_in[0];
  const float* W = (const float*)d_in[1];
  const float* att_src = (const float*)d_in[2];
  const float* att_dst = (const float*)d_in[3];
  const float* bias = (const float*)d_in[4];
  const int* ei = (const int*)d_in[5];
  float* out = (float*)d_out;

  // workspace layout
  unsigned short* h2 = (unsigned short*)d_ws;            // MPAD*768 bf16
  unsigned short* xbf = h2 + (size_t)MPAD * HD;          // MPAD*768 bf16
  unsigned short* wt = xbf + (size_t)MPAD * HD;          // 768*768 bf16
  float* asrc = (float*)(wt + (size_t)HD * Cv);          // 120,000 f32
  float* adst = asrc + (size_t)Bv * Nv * Hv;             // 120,000 f32
  int* counts = (int*)(adst + (size_t)Bv * Nv * Hv);     // Nv
  int* cursor = counts + Nv;                             // Nv
  int* offsets = cursor + Nv;                            // Nv+1
  int* csr = offsets + Nv + 1;                           // ETOT

  hipMemsetAsync(counts, 0, sizeof(int) * 2 * Nv, stream);

  k_cvt_x<<<(int)(((size_t)MPAD * HD / 8 + 255) / 256), 256, 0, stream>>>(x, xbf);
  k_cvt_wt<<<dim3(HD / 32, Cv / 32), dim3(32, 8), 0, stream>>>(W, wt);
  k_gemm_mfma<<<dim3(HD / 128, MPAD / 128), 256, 0, stream>>>(xbf, wt, h2, att_src, att_dst, asrc, adst);
  k_count<<<(ETOT + 255) / 256, 256, 0, stream>>>(ei, counts);
  k_scan<<<1, 1024, 0, stream>>>(counts, offsets);
  k_scatter<<<(ETOT + 255) / 256, 256, 0, stream>>>(ei, offsets, cursor, csr);
  k_agg<<<Bv * Nv, 192, 0, stream>>>(h2, ei, offsets, csr, asrc, adst, bias, out);
}